// Round 1
// baseline (263.431 us; speedup 1.0000x reference)
//
#include <hip/hip_runtime.h>

typedef __attribute__((ext_vector_type(8))) short bf16x8;
typedef __attribute__((ext_vector_type(4))) float f32x4;
typedef __attribute__((ext_vector_type(2))) unsigned int u32x2;
typedef unsigned int u32;
typedef unsigned short u16;

constexpr int Bb = 4, S = 2048, D = 1024, H = 16, DK = 64, M = Bb * S;

#if __has_builtin(__builtin_amdgcn_exp2f)
#define EXP2F __builtin_amdgcn_exp2f
#else
#define EXP2F exp2f
#endif

__device__ __forceinline__ u16 f2bf(float f) {
  u32 u = __float_as_uint(f);
  return (u16)((u + 0x7fffu + ((u >> 16) & 1u)) >> 16);
}

__device__ __forceinline__ void gld_lds16(const u16* g, u16* l) {
  __builtin_amdgcn_global_load_lds((const __attribute__((address_space(1))) u32*)g,
                                   (__attribute__((address_space(3))) u32*)l, 16, 0, 0);
}

__global__ void cast_kernel(const float* __restrict__ s, u16* __restrict__ d, int n) {
  int i = (blockIdx.x * blockDim.x + threadIdx.x) * 4;
  if (i >= n) return;
  float4 f = *(const float4*)(s + i);
  ushort4 o;
  o.x = f2bf(f.x); o.y = f2bf(f.y); o.z = f2bf(f.z); o.w = f2bf(f.w);
  *(ushort4*)(d + i) = o;
}

struct CastArgs { const float* s[4]; u16* d[4]; float sc[4]; };
__global__ void cast4_kernel(CastArgs a) {
  int i = (blockIdx.x * blockDim.x + threadIdx.x) * 4;
  int w = i >> 20;
  int off = i & ((1 << 20) - 1);
  float sc = a.sc[w];
  float4 f = *(const float4*)(a.s[w] + off);
  ushort4 o;
  o.x = f2bf(f.x * sc); o.y = f2bf(f.y * sc); o.z = f2bf(f.z * sc); o.w = f2bf(f.w * sc);
  *(ushort4*)(a.d[w] + off) = o;
}

// ---- GEMM core: C[m,n] = sum_k A[m,k]*Bt[n,k], 128x128 tile, BK=64 ----
template <bool OUTF32>
__device__ __forceinline__ void gemm_core(const u16* __restrict__ A,
                                          const u16* __restrict__ Bt,
                                          float* __restrict__ Cf, u16* __restrict__ Cb,
                                          int Nn, int Kk, int m0, int n0,
                                          u16* As, u16* Bs) {
  const int tid = threadIdx.x, wave = tid >> 6, lane = tid & 63;
  const int quad = lane >> 4, col = lane & 15;
  const int wm = wave >> 1, wn = wave & 1;

  f32x4 acc[4][4];
#pragma unroll
  for (int i = 0; i < 4; i++)
#pragma unroll
    for (int j = 0; j < 4; j++) acc[i][j] = (f32x4){0.f, 0.f, 0.f, 0.f};

  for (int k0 = 0; k0 < Kk; k0 += 64) {
#pragma unroll
    for (int j = 0; j < 4; j++) {
      int g = (wave * 4 + j) * 64;
      int gl = g + lane;
      int r = gl >> 3, sl = gl & 7;
      int kof = (sl ^ (r & 7)) * 8;
      const u16* ga = A + (size_t)(m0 + r) * Kk + k0 + kof;
      gld_lds16(ga, &As[g * 8]);
      const u16* gb = Bt + (size_t)(n0 + r) * Kk + k0 + kof;
      gld_lds16(gb, &Bs[g * 8]);
    }
    __syncthreads();
#pragma unroll
    for (int kb = 0; kb < 2; kb++) {
      bf16x8 af[4], bfr[4];
#pragma unroll
      for (int mi = 0; mi < 4; mi++) {
        int R = wm * 64 + mi * 16 + col;
        af[mi] = *(const bf16x8*)&As[R * 64 + (((kb * 4 + quad) ^ (R & 7)) << 3)];
      }
#pragma unroll
      for (int ni = 0; ni < 4; ni++) {
        int R = wn * 64 + ni * 16 + col;
        bfr[ni] = *(const bf16x8*)&Bs[R * 64 + (((kb * 4 + quad) ^ (R & 7)) << 3)];
      }
#pragma unroll
      for (int mi = 0; mi < 4; mi++)
#pragma unroll
        for (int ni = 0; ni < 4; ni++)
          acc[mi][ni] = __builtin_amdgcn_mfma_f32_16x16x32_bf16(af[mi], bfr[ni], acc[mi][ni], 0, 0, 0);
    }
    __syncthreads();
  }
#pragma unroll
  for (int mi = 0; mi < 4; mi++)
#pragma unroll
    for (int ni = 0; ni < 4; ni++)
#pragma unroll
      for (int r = 0; r < 4; r++) {
        int row = m0 + wm * 64 + mi * 16 + quad * 4 + r;
        int cc = n0 + wn * 64 + ni * 16 + col;
        float v = acc[mi][ni][r];
        if (OUTF32) Cf[(size_t)row * Nn + cc] = v;
        else Cb[(size_t)row * Nn + cc] = f2bf(v);
      }
}

struct QkvArgs { const u16* bt[3]; u16* c[3]; };
__global__ __launch_bounds__(256) void gemm_qkv(const u16* __restrict__ A, QkvArgs q) {
  __shared__ __align__(16) u16 As[128 * 64];
  __shared__ __align__(16) u16 Bs[128 * 64];
  int sel = blockIdx.x >> 3;
  int n0 = (blockIdx.x & 7) * 128, m0 = blockIdx.y * 128;
  gemm_core<false>(A, q.bt[sel], nullptr, q.c[sel], D, D, m0, n0, As, Bs);
}

__global__ __launch_bounds__(256) void gemm_f32(const u16* __restrict__ A,
                                                const u16* __restrict__ Bt,
                                                float* __restrict__ C) {
  __shared__ __align__(16) u16 As[128 * 64];
  __shared__ __align__(16) u16 Bs[128 * 64];
  gemm_core<true>(A, Bt, C, nullptr, D, D, blockIdx.y * 128, blockIdx.x * 128, As, Bs);
}

// ---- flash attention, causal ----
// Pair-of-q-blocks per block (uniform 34 k-iters). K double-buffered in LDS
// via global_load_lds DMA (global source pre-swizzled: slot = chunk ^
// ((key>>1)&3), linear LDS dest). V double-buffered regs->LDS transposed,
// slot = (key>>3) ^ (d&7) => conflict-free b128 reads. QK^T computed
// SWAPPED (mfma(K,Q)) so each lane holds 4 consecutive keys per acc group
// for q=col: P stored as 8 packed ds_write_b64 (was 32 scalar b16), into
// slot = (key>>3) ^ (q&7) swizzled rows. Row sums via ones-MFMA.
__global__ __launch_bounds__(256) void attn_kernel(const u16* __restrict__ Q,
                                                   const u16* __restrict__ K,
                                                   const u16* __restrict__ V,
                                                   u16* __restrict__ O) {
  __shared__ __align__(16) u16 Ks[2][2][64 * 32];  // [buf][d-half][key*32 + swz-slot]
  __shared__ __align__(16) u16 Vt[2][64 * 64];     // [buf] V^T [d][key-swizzled]
  __shared__ __align__(16) u16 Pw[4][32 * 64];     // per-wave P [q][key-swizzled]
  const int tid = threadIdx.x, wave = tid >> 6, lane = tid & 63;
  const int quad = lane >> 4, col = lane & 15;
  const int bh = blockIdx.x, b = bh >> 4, h = bh & 15;
  const int pair = blockIdx.y;  // 0..7
  const size_t base = (size_t)b * S * D + h * DK;

  // V staging distribution: thread handles keys (vk0, vk0+1) x 8 d's
  const int vk0 = (tid & 31) * 2;
  const int vdg = tid >> 5;  // d-group 0..7

  bf16x8 bones;
#pragma unroll
  for (int e = 0; e < 8; e++) bones[e] = (short)0x3F80;  // bf16 1.0

  // K DMA: linear LDS dest, source d-chunk pre-swizzled: chunk = slot ^ ((key>>1)&3)
  auto kdma = [&](int ktile, int buf) {
    int c = tid, cb = wave * 64;
    int kk = c >> 2;
    int dch = (c & 3) ^ ((kk >> 1) & 3);
    const u16* g0 = K + base + (size_t)(ktile * 64 + kk) * D + dch * 8;
    gld_lds16(g0, &Ks[buf][0][cb * 8]);
    gld_lds16(g0 + 32, &Ks[buf][1][cb * 8]);
  };

  for (int half = 0; half < 2; half++) {
    const int qb = half ? pair : 15 - pair;
    const int qw = qb * 128 + wave * 32;
    const int nkt = 2 * qb + 2;  // even

    bf16x8 aq[2][2];
#pragma unroll
    for (int mi = 0; mi < 2; mi++)
#pragma unroll
      for (int kb = 0; kb < 2; kb++)
        aq[mi][kb] = *(const bf16x8*)(Q + base + (size_t)(qw + mi * 16 + col) * D + kb * 32 + quad * 8);

    f32x4 ao[2][4], lacc[2];
#pragma unroll
    for (int mi = 0; mi < 2; mi++) {
      lacc[mi] = (f32x4){0.f, 0.f, 0.f, 0.f};
#pragma unroll
      for (int dg = 0; dg < 4; dg++) ao[mi][dg] = (f32x4){0.f, 0.f, 0.f, 0.f};
    }

    // regs A hold even V-tiles, regs B hold odd V-tiles
    bf16x8 vA0, vA1, vB0, vB1;
    {
      const u16* vp = V + base + (size_t)vk0 * D + vdg * 8;
      vA0 = *(const bf16x8*)vp; vA1 = *(const bf16x8*)(vp + D);
    }
    __syncthreads();  // previous half's LDS readers done before restaging
    kdma(0, 0);
    auto vstage = [&](int buf, bf16x8 r0, bf16x8 r1) {
      int kgrp = vk0 >> 3, kin = vk0 & 7;
#pragma unroll
      for (int e = 0; e < 8; e++) {
        u32 val = ((u32)(u16)r0[e]) | ((u32)(u16)r1[e] << 16);
        int slot = (kgrp ^ e) & 7;  // d&7 == e
        *(u32*)&Vt[buf][(vdg * 8 + e) * 64 + (slot << 3) + kin] = val;
      }
    };
    vstage(0, vA0, vA1);
    {  // V(1) -> B (nkt >= 2 always)
      const u16* vp = V + base + (size_t)(64 + vk0) * D + vdg * 8;
      vB0 = *(const bf16x8*)vp; vB1 = *(const bf16x8*)(vp + D);
    }

    for (int kt = 0; kt < nkt; kt++) {
      const int bf = kt & 1, nb = bf ^ 1, ph = kt & 1;
      __syncthreads();  // drains K(kt) DMA + V(kt+1) regs; publishes Vt[bf]
      const bool active = (kt * 64 <= qw + 31);  // wave-uniform
      if (kt + 1 < nkt) {
        kdma(kt + 1, nb);  // a full iteration for the DMA to land
        // stage V(kt+1): odd tiles from B, even from A
        vstage(nb, ph ? vA0 : vB0, ph ? vA1 : vB1);
        if (kt + 2 < nkt) {  // V(kt+2) -> (even ? A : B)
          const u16* vp = V + base + (size_t)((kt + 2) * 64 + vk0) * D + vdg * 8;
          if (ph) { vB0 = *(const bf16x8*)vp; vB1 = *(const bf16x8*)(vp + D); }
          else    { vA0 = *(const bf16x8*)vp; vA1 = *(const bf16x8*)(vp + D); }
        }
      }
      if (!active) continue;
      // K fragments from Ks[bf] (swizzle: slot = quad ^ ((key>>1)&3))
      bf16x8 bk0[4], bk1[4];
      const int ksl = ((quad ^ ((col >> 1) & 3)) & 3) << 3;
#pragma unroll
      for (int n16 = 0; n16 < 4; n16++) {
        bk0[n16] = *(const bf16x8*)&Ks[bf][0][(n16 * 16 + col) * 32 + ksl];
        bk1[n16] = *(const bf16x8*)&Ks[bf][1][(n16 * 16 + col) * 32 + ksl];
      }
      // Swapped QK^T: A = K (m = key), B = Q (n = q).
      // C[m = n16*16 + quad*4 + r][n = qi*16 + col]
      f32x4 sacc[2][4];
#pragma unroll
      for (int qi = 0; qi < 2; qi++)
#pragma unroll
        for (int n16 = 0; n16 < 4; n16++) sacc[qi][n16] = (f32x4){0.f, 0.f, 0.f, 0.f};
      __builtin_amdgcn_s_setprio(1);
#pragma unroll
      for (int qi = 0; qi < 2; qi++)
#pragma unroll
        for (int n16 = 0; n16 < 4; n16++) {
          sacc[qi][n16] = __builtin_amdgcn_mfma_f32_16x16x32_bf16(bk0[n16], aq[qi][0], sacc[qi][n16], 0, 0, 0);
          sacc[qi][n16] = __builtin_amdgcn_mfma_f32_16x16x32_bf16(bk1[n16], aq[qi][1], sacc[qi][n16], 0, 0, 0);
        }
      __builtin_amdgcn_s_setprio(0);
      const bool full = (kt * 64 + 63) <= qw;  // wave-uniform: no masking
      // p = exp2(s); lane holds keys n16*16+quad*4+{0..3} for q = qi*16+col
      // => pack 4 bf16 (trunc) into one ds_write_b64 per (qi,n16).
#pragma unroll
      for (int qi = 0; qi < 2; qi++) {
        const int row = qi * 16 + col;
        const int rsw = row & 7;
        const int qg = qw + row;
#pragma unroll
        for (int n16 = 0; n16 < 4; n16++) {
          float p0 = EXP2F(sacc[qi][n16][0]);
          float p1 = EXP2F(sacc[qi][n16][1]);
          float p2 = EXP2F(sacc[qi][n16][2]);
          float p3 = EXP2F(sacc[qi][n16][3]);
          if (!full) {
            int kg = kt * 64 + n16 * 16 + quad * 4;
            p0 = (kg + 0 > qg) ? 0.f : p0;
            p1 = (kg + 1 > qg) ? 0.f : p1;
            p2 = (kg + 2 > qg) ? 0.f : p2;
            p3 = (kg + 3 > qg) ? 0.f : p3;
          }
          u32 lo = (__float_as_uint(p0) >> 16) | (__float_as_uint(p1) & 0xFFFF0000u);
          u32 hi = (__float_as_uint(p2) >> 16) | (__float_as_uint(p3) & 0xFFFF0000u);
          int slot = ((n16 * 2 + (quad >> 1)) ^ rsw) & 7;
          *(u32x2*)&Pw[wave][row * 64 + (slot << 3) + ((quad & 1) << 2)] = (u32x2){lo, hi};
        }
      }
      // PV + ones-MFMA row sums (same-wave LDS write->read, no barrier)
      bf16x8 bv[2][4];
#pragma unroll
      for (int kb = 0; kb < 2; kb++)
#pragma unroll
        for (int dg = 0; dg < 4; dg++)
          bv[kb][dg] = *(const bf16x8*)&Vt[bf][(dg * 16 + col) * 64 + ((((kb * 4 + quad) ^ (col & 7)) & 7) << 3)];
#pragma unroll
      for (int mi = 0; mi < 2; mi++) {
        const int row = mi * 16 + col;
        const int rsw = row & 7;
        bf16x8 ap0 = *(const bf16x8*)&Pw[wave][row * 64 + (((quad ^ rsw) & 7) << 3)];
        bf16x8 ap1 = *(const bf16x8*)&Pw[wave][row * 64 + ((((4 + quad) ^ rsw) & 7) << 3)];
        __builtin_amdgcn_s_setprio(1);
#pragma unroll
        for (int dg = 0; dg < 4; dg++) {
          ao[mi][dg] = __builtin_amdgcn_mfma_f32_16x16x32_bf16(ap0, bv[0][dg], ao[mi][dg], 0, 0, 0);
          ao[mi][dg] = __builtin_amdgcn_mfma_f32_16x16x32_bf16(ap1, bv[1][dg], ao[mi][dg], 0, 0, 0);
        }
        lacc[mi] = __builtin_amdgcn_mfma_f32_16x16x32_bf16(ap0, bones, lacc[mi], 0, 0, 0);
        lacc[mi] = __builtin_amdgcn_mfma_f32_16x16x32_bf16(ap1, bones, lacc[mi], 0, 0, 0);
        __builtin_amdgcn_s_setprio(0);
      }
    }
    // epilogue: normalize + write O
#pragma unroll
    for (int mi = 0; mi < 2; mi++)
#pragma unroll
      for (int r = 0; r < 4; r++) {
        float inv = 1.f / lacc[mi][r];
        int q = qw + mi * 16 + quad * 4 + r;
#pragma unroll
        for (int dg = 0; dg < 4; dg++)
          O[base + (size_t)q * D + dg * 16 + col] = f2bf(ao[mi][dg][r] * inv);
      }
  }
}

extern "C" void kernel_launch(void* const* d_in, const int* in_sizes, int n_in,
                              void* d_out, int out_size, void* d_ws, size_t ws_size,
                              hipStream_t stream) {
  const float* x  = (const float*)d_in[0];
  const float* Wq = (const float*)d_in[1];
  const float* Wk = (const float*)d_in[2];
  const float* Wv = (const float*)d_in[3];
  const float* Wo = (const float*)d_in[4];

  u16* xb  = (u16*)d_ws;
  u16* wqb = xb + (size_t)M * D;
  u16* wkb = wqb + (size_t)D * D;
  u16* wvb = wkb + (size_t)D * D;
  u16* wob = wvb + (size_t)D * D;
  u16* Qb  = wob + (size_t)D * D;
  u16* Kb  = Qb + (size_t)M * D;
  u16* Vb  = Kb + (size_t)M * D;
  u16* Ab  = xb;  // x dead after projections

  cast_kernel<<<M * D / 1024, 256, 0, stream>>>(x, xb, M * D);
  CastArgs ca;
  ca.s[0] = Wq; ca.s[1] = Wk; ca.s[2] = Wv; ca.s[3] = Wo;
  ca.d[0] = wqb; ca.d[1] = wkb; ca.d[2] = wvb; ca.d[3] = wob;
  ca.sc[0] = 0.18033688011112042f;  // 0.125 * log2(e) folded into Wq
  ca.sc[1] = 1.f; ca.sc[2] = 1.f; ca.sc[3] = 1.f;
  cast4_kernel<<<4 * D * D / 1024, 256, 0, stream>>>(ca);

  QkvArgs qa;
  qa.bt[0] = wqb; qa.bt[1] = wkb; qa.bt[2] = wvb;
  qa.c[0] = Qb; qa.c[1] = Kb; qa.c[2] = Vb;
  gemm_qkv<<<dim3(24, M / 128), 256, 0, stream>>>(xb, qa);

  attn_kernel<<<dim3(Bb * H, 8), 256, 0, stream>>>(Qb, Kb, Vb, Ab);

  gemm_f32<<<dim3(D / 128, M / 128), 256, 0, stream>>>(Ab, wob, (float*)d_out);
}